// Round 1
// baseline (13788.066 us; speedup 1.0000x reference)
//
#include <hip/hip_runtime.h>

#define BTOT 8192
#define T 512
#define INW 8
#define HID 64
#define G4 256   // 4*HID
#define NB 8     // batch elements per block
#define TS 64    // timesteps per x-chunk staged in LDS

__global__ __launch_bounds__(256) void lstm_fused_kernel(
    const float* __restrict__ x,      // [B, T, IN]
    const float* __restrict__ W_ih,   // [4H, IN]
    const float* __restrict__ W_hh,   // [4H, H]
    const float* __restrict__ b_ih,   // [4H]
    const float* __restrict__ b_hh,   // [4H]
    const float* __restrict__ W_fc,   // [2, H]
    const float* __restrict__ b_fc,   // [2]
    float* __restrict__ out)          // [B, 2]
{
    __shared__ alignas(16) float xbuf[NB * TS * INW];   // 16 KB
    __shared__ alignas(16) float h_lds[NB * HID];       // 2 KB
    __shared__ alignas(16) float gate_lds[NB * G4];     // 8 KB

    const int tid = threadIdx.x;        // 0..255 == gate row g
    const int g = tid;
    const int batch0 = blockIdx.x * NB;

    // ---- persistent per-thread weights: row g of W_hh, W_ih, bias ----
    float whh[HID];
    #pragma unroll
    for (int kk = 0; kk < HID / 4; ++kk) {
        float4 w = reinterpret_cast<const float4*>(W_hh)[g * (HID / 4) + kk];
        whh[4 * kk + 0] = w.x; whh[4 * kk + 1] = w.y;
        whh[4 * kk + 2] = w.z; whh[4 * kk + 3] = w.w;
    }
    float wih[INW];
    {
        float4 w0 = reinterpret_cast<const float4*>(W_ih)[g * 2 + 0];
        float4 w1 = reinterpret_cast<const float4*>(W_ih)[g * 2 + 1];
        wih[0] = w0.x; wih[1] = w0.y; wih[2] = w0.z; wih[3] = w0.w;
        wih[4] = w1.x; wih[5] = w1.y; wih[6] = w1.z; wih[7] = w1.w;
    }
    const float bias = b_ih[g] + b_hh[g];

    // update-phase mapping: this thread owns states (b0,j) and (b1,j)
    const int j  = tid & 63;       // == lane id within wave
    const int b0 = tid >> 6;       // 0..3
    const int b1 = b0 + 4;         // 4..7
    float c0 = 0.0f, c1 = 0.0f;

    // wave-uniform activation selector (wave2 of each gate-group = tanh)
    const bool is_tanh_gate = (g >= 128 && g < 192);

    // init h = 0
    h_lds[tid] = 0.0f;
    h_lds[tid + 256] = 0.0f;   // NB*HID = 512

    #pragma unroll 1
    for (int tc = 0; tc < T / TS; ++tc) {
        __syncthreads();                 // xbuf free; also covers h init at tc=0
        // ---- stage x chunk: NB segments of TS*IN floats, coalesced f4 ----
        {
            const float4* xs = reinterpret_cast<const float4*>(x);
            float4* xd = reinterpret_cast<float4*>(xbuf);
            #pragma unroll
            for (int it = 0; it < (NB * TS * INW / 4) / 256; ++it) {
                int idx = it * 256 + tid;          // float4 index
                int b = idx >> 7;                  // /128 f4 per segment
                int l = idx & 127;
                xd[idx] = xs[(size_t)(batch0 + b) * (T * INW / 4) + tc * (TS * INW / 4) + l];
            }
        }
        __syncthreads();

        #pragma unroll 1
        for (int tt = 0; tt < TS; ++tt) {
            // ---- gate phase: thread g computes gate row g for NB elems ----
            float acc[NB];
            #pragma unroll
            for (int b = 0; b < NB; ++b) acc[b] = bias;

            #pragma unroll
            for (int b = 0; b < NB; ++b) {
                const float4* xv = reinterpret_cast<const float4*>(xbuf)
                                   + b * (TS * INW / 4) + tt * 2;
                float4 x0 = xv[0], x1 = xv[1];
                acc[b] = fmaf(wih[0], x0.x, acc[b]);
                acc[b] = fmaf(wih[1], x0.y, acc[b]);
                acc[b] = fmaf(wih[2], x0.z, acc[b]);
                acc[b] = fmaf(wih[3], x0.w, acc[b]);
                acc[b] = fmaf(wih[4], x1.x, acc[b]);
                acc[b] = fmaf(wih[5], x1.y, acc[b]);
                acc[b] = fmaf(wih[6], x1.z, acc[b]);
                acc[b] = fmaf(wih[7], x1.w, acc[b]);
            }
            #pragma unroll
            for (int b = 0; b < NB; ++b) {
                const float4* hv4 = reinterpret_cast<const float4*>(h_lds) + b * (HID / 4);
                #pragma unroll
                for (int kk = 0; kk < HID / 4; ++kk) {
                    float4 hv = hv4[kk];
                    acc[b] = fmaf(whh[4 * kk + 0], hv.x, acc[b]);
                    acc[b] = fmaf(whh[4 * kk + 1], hv.y, acc[b]);
                    acc[b] = fmaf(whh[4 * kk + 2], hv.z, acc[b]);
                    acc[b] = fmaf(whh[4 * kk + 3], hv.w, acc[b]);
                }
            }
            #pragma unroll
            for (int b = 0; b < NB; ++b) {
                float a;
                if (is_tanh_gate) {
                    a = 1.0f - 2.0f / (__expf(2.0f * acc[b]) + 1.0f);   // tanh
                } else {
                    a = 1.0f / (1.0f + __expf(-acc[b]));                // sigmoid
                }
                gate_lds[b * G4 + g] = a;
            }
            __syncthreads();

            // ---- update phase: c,h for (b0,j) and (b1,j) ----
            {
                float iv = gate_lds[b0 * G4 + j];
                float fv = gate_lds[b0 * G4 + 64 + j];
                float gv = gate_lds[b0 * G4 + 128 + j];
                float ov = gate_lds[b0 * G4 + 192 + j];
                c0 = fmaf(fv, c0, iv * gv);
                float th = 1.0f - 2.0f / (__expf(2.0f * c0) + 1.0f);
                h_lds[b0 * HID + j] = ov * th;
            }
            {
                float iv = gate_lds[b1 * G4 + j];
                float fv = gate_lds[b1 * G4 + 64 + j];
                float gv = gate_lds[b1 * G4 + 128 + j];
                float ov = gate_lds[b1 * G4 + 192 + j];
                c1 = fmaf(fv, c1, iv * gv);
                float th = 1.0f - 2.0f / (__expf(2.0f * c1) + 1.0f);
                h_lds[b1 * HID + j] = ov * th;
            }
            __syncthreads();
        }
    }

    // ---- final FC: out[b] = h_last . W_fc[row] + b_fc ----
    {
        float h0 = h_lds[b0 * HID + j];
        float h1 = h_lds[b1 * HID + j];
        float w0 = W_fc[j];
        float w1 = W_fc[HID + j];
        float a0 = h0 * w0, a1 = h0 * w1;
        float a2 = h1 * w0, a3 = h1 * w1;
        #pragma unroll
        for (int off = 32; off > 0; off >>= 1) {
            a0 += __shfl_down(a0, off, 64);
            a1 += __shfl_down(a1, off, 64);
            a2 += __shfl_down(a2, off, 64);
            a3 += __shfl_down(a3, off, 64);
        }
        if (j == 0) {
            float bo0 = b_fc[0], bo1 = b_fc[1];
            out[(size_t)(batch0 + b0) * 2 + 0] = a0 + bo0;
            out[(size_t)(batch0 + b0) * 2 + 1] = a1 + bo1;
            out[(size_t)(batch0 + b1) * 2 + 0] = a2 + bo0;
            out[(size_t)(batch0 + b1) * 2 + 1] = a3 + bo1;
        }
    }
}

extern "C" void kernel_launch(void* const* d_in, const int* in_sizes, int n_in,
                              void* d_out, int out_size, void* d_ws, size_t ws_size,
                              hipStream_t stream) {
    const float* x    = (const float*)d_in[0];
    const float* W_ih = (const float*)d_in[1];
    const float* W_hh = (const float*)d_in[2];
    const float* b_ih = (const float*)d_in[3];
    const float* b_hh = (const float*)d_in[4];
    const float* W_fc = (const float*)d_in[5];
    const float* b_fc = (const float*)d_in[6];
    float* out = (float*)d_out;

    dim3 grid(BTOT / NB);   // 1024 blocks
    dim3 block(256);
    lstm_fused_kernel<<<grid, block, 0, stream>>>(x, W_ih, W_hh, b_ih, b_hh,
                                                  W_fc, b_fc, out);
}

// Round 2
// 4538.449 us; speedup vs baseline: 3.0381x; 3.0381x over previous
//
#include <hip/hip_runtime.h>

#define BTOT 8192
#define T 512
#define INW 8
#define HID 64
#define G4 256   // 4*HID
#define NB 8     // batch elements per block
#define TS 64    // timesteps per x-chunk staged in LDS

__device__ __forceinline__ float fast_rcp(float x) { return __builtin_amdgcn_rcpf(x); }
__device__ __forceinline__ float sigm_f(float x) { return fast_rcp(1.0f + __expf(-x)); }
__device__ __forceinline__ float tanh_f(float x) { return 1.0f - 2.0f * fast_rcp(__expf(2.0f * x) + 1.0f); }

__global__ __launch_bounds__(256, 2) void lstm_fused_kernel(
    const float* __restrict__ x,      // [B, T, IN]
    const float* __restrict__ W_ih,   // [4H, IN]
    const float* __restrict__ W_hh,   // [4H, H]
    const float* __restrict__ b_ih,   // [4H]
    const float* __restrict__ b_hh,   // [4H]
    const float* __restrict__ W_fc,   // [2, H]
    const float* __restrict__ b_fc,   // [2]
    float* __restrict__ out)          // [B, 2]
{
    __shared__ alignas(16) float xbuf[NB * TS * INW];   // 16 KB
    __shared__ alignas(16) float h_lds[NB * HID];       // 2 KB
    __shared__ alignas(16) float gate_lds[NB * G4];     // 8 KB

    const int tid = threadIdx.x;        // 0..255 == gate row g
    const int g = tid;
    const int batch0 = blockIdx.x * NB;

    // ---- persistent per-thread weights: row g of W_hh (as float4), W_ih, bias ----
    float4 whh4[HID / 4];
    #pragma unroll
    for (int kk = 0; kk < HID / 4; ++kk)
        whh4[kk] = reinterpret_cast<const float4*>(W_hh)[g * (HID / 4) + kk];

    float4 wihA = reinterpret_cast<const float4*>(W_ih)[g * 2 + 0];
    float4 wihB = reinterpret_cast<const float4*>(W_ih)[g * 2 + 1];
    const float bias = b_ih[g] + b_hh[g];

    // update-phase mapping: this thread owns states (b0,j) and (b1,j)
    const int j  = tid & 63;       // lane id within wave
    const int b0 = tid >> 6;       // 0..3
    const int b1 = b0 + 4;         // 4..7
    float c0 = 0.0f, c1 = 0.0f;

    // wave-uniform activation selector (gate rows 128..191 = g-gate = tanh)
    const bool is_tanh_gate = (g >= 128 && g < 192);

    // init h = 0
    h_lds[tid] = 0.0f;
    h_lds[tid + 256] = 0.0f;   // NB*HID = 512

    const float4* h4 = reinterpret_cast<const float4*>(h_lds);

    #pragma unroll 1
    for (int tc = 0; tc < T / TS; ++tc) {
        __syncthreads();                 // xbuf free; also covers h init at tc=0
        // ---- stage x chunk: NB segments of TS*IN floats, coalesced f4 ----
        {
            const float4* xs = reinterpret_cast<const float4*>(x);
            float4* xd = reinterpret_cast<float4*>(xbuf);
            #pragma unroll
            for (int it = 0; it < (NB * TS * INW / 4) / 256; ++it) {
                int idx = it * 256 + tid;          // float4 index
                int b = idx >> 7;                  // 128 f4 per segment
                int l = idx & 127;
                xd[idx] = xs[(size_t)(batch0 + b) * (T * INW / 4) + tc * (TS * INW / 4) + l];
            }
        }
        __syncthreads();

        #pragma unroll 1
        for (int tt = 0; tt < TS; ++tt) {
            // ---- gate phase: thread g computes gate row g for NB batch elems ----
            float acc[NB];

            // x-projection part (+bias)
            #pragma unroll
            for (int b = 0; b < NB; ++b) {
                const float4* xv = reinterpret_cast<const float4*>(xbuf)
                                   + b * (TS * INW / 4) + tt * 2;
                float4 x0 = xv[0], x1 = xv[1];
                float a = bias;
                a = fmaf(wihA.x, x0.x, a);
                a = fmaf(wihA.y, x0.y, a);
                a = fmaf(wihA.z, x0.z, a);
                a = fmaf(wihA.w, x0.w, a);
                a = fmaf(wihB.x, x1.x, a);
                a = fmaf(wihB.y, x1.y, a);
                a = fmaf(wihB.z, x1.z, a);
                a = fmaf(wihB.w, x1.w, a);
                acc[b] = a;
            }

            // recurrent part: acc[b] += W_hh[g][:] . h[b][:]
            #pragma unroll 2
            for (int kk = 0; kk < HID / 4; ++kk) {
                float4 w = whh4[kk];
                #pragma unroll
                for (int b = 0; b < NB; ++b) {
                    float4 hv = h4[b * (HID / 4) + kk];
                    float a = acc[b];
                    a = fmaf(w.x, hv.x, a);
                    a = fmaf(w.y, hv.y, a);
                    a = fmaf(w.z, hv.z, a);
                    a = fmaf(w.w, hv.w, a);
                    acc[b] = a;
                }
            }

            // activation (wave-uniform branch) + write gate value
            #pragma unroll
            for (int b = 0; b < NB; ++b) {
                float a = is_tanh_gate ? tanh_f(acc[b]) : sigm_f(acc[b]);
                gate_lds[b * G4 + g] = a;
            }
            __syncthreads();

            // ---- update phase: c,h for (b0,j) and (b1,j) ----
            {
                float iv = gate_lds[b0 * G4 + j];
                float fv = gate_lds[b0 * G4 + 64 + j];
                float gv = gate_lds[b0 * G4 + 128 + j];
                float ov = gate_lds[b0 * G4 + 192 + j];
                c0 = fmaf(fv, c0, iv * gv);
                h_lds[b0 * HID + j] = ov * tanh_f(c0);
            }
            {
                float iv = gate_lds[b1 * G4 + j];
                float fv = gate_lds[b1 * G4 + 64 + j];
                float gv = gate_lds[b1 * G4 + 128 + j];
                float ov = gate_lds[b1 * G4 + 192 + j];
                c1 = fmaf(fv, c1, iv * gv);
                h_lds[b1 * HID + j] = ov * tanh_f(c1);
            }
            __syncthreads();
        }
    }

    // ---- final FC: out[b] = h_last . W_fc[row] + b_fc ----
    {
        float h0 = h_lds[b0 * HID + j];
        float h1 = h_lds[b1 * HID + j];
        float w0 = W_fc[j];
        float w1 = W_fc[HID + j];
        float a0 = h0 * w0, a1 = h0 * w1;
        float a2 = h1 * w0, a3 = h1 * w1;
        #pragma unroll
        for (int off = 32; off > 0; off >>= 1) {
            a0 += __shfl_down(a0, off, 64);
            a1 += __shfl_down(a1, off, 64);
            a2 += __shfl_down(a2, off, 64);
            a3 += __shfl_down(a3, off, 64);
        }
        if (j == 0) {
            float bo0 = b_fc[0], bo1 = b_fc[1];
            out[(size_t)(batch0 + b0) * 2 + 0] = a0 + bo0;
            out[(size_t)(batch0 + b0) * 2 + 1] = a1 + bo1;
            out[(size_t)(batch0 + b1) * 2 + 0] = a2 + bo0;
            out[(size_t)(batch0 + b1) * 2 + 1] = a3 + bo1;
        }
    }
}

extern "C" void kernel_launch(void* const* d_in, const int* in_sizes, int n_in,
                              void* d_out, int out_size, void* d_ws, size_t ws_size,
                              hipStream_t stream) {
    const float* x    = (const float*)d_in[0];
    const float* W_ih = (const float*)d_in[1];
    const float* W_hh = (const float*)d_in[2];
    const float* b_ih = (const float*)d_in[3];
    const float* b_hh = (const float*)d_in[4];
    const float* W_fc = (const float*)d_in[5];
    const float* b_fc = (const float*)d_in[6];
    float* out = (float*)d_out;

    dim3 grid(BTOT / NB);   // 1024 blocks
    dim3 block(256);
    lstm_fused_kernel<<<grid, block, 0, stream>>>(x, W_ih, W_hh, b_ih, b_hh,
                                                  W_fc, b_fc, out);
}